// Round 6
// baseline (48.097 us; speedup 1.0000x reference)
//
#include <hip/hip_runtime.h>
#include <hip/hip_bf16.h>
#include <stdint.h>

// Fused single-head causal attention: q=x@Wq, k=x@Wk, v=x@Wv,
// out = softmax(causal(q k^T/8)) @ v.  B=256, T=256, C=768, H=64.
// One block per batch (256 blocks = 1 per CU), 512 threads (8 waves).
// Phase 1: x+Wt double-buffered LDS, 2-deep register prefetch, lgkmcnt-only
//   barriers (in-flight global loads survive barriers).
// Phase 2 (R6): swapped QK^T (lane holds 4 consecutive keys -> b64 P writes),
//   balanced causal pairing (w, 15-w): every wave 17 key-tiles; no max-sub
//   (scores bounded); deferred normalization; PV operand-swapped so O comes
//   out transposed (lane holds 4 consecutive h -> float4 out stores, and
//   1/sum is already lane-correct: no shfl broadcast).

typedef __attribute__((ext_vector_type(8))) short short8;
typedef __attribute__((ext_vector_type(4))) short short4v;
typedef __attribute__((ext_vector_type(4))) float f32x4;

#define MFMA16(a, b, c) __builtin_amdgcn_mfma_f32_16x16x32_bf16(a, b, c, 0, 0, 0)

// barrier that does NOT drain vmcnt: LDS visibility only.
#define BAR() do { \
  asm volatile("s_waitcnt lgkmcnt(0)" ::: "memory"); \
  __builtin_amdgcn_s_barrier(); \
} while (0)

static __device__ __forceinline__ unsigned short f2bf(float f) {
  union { float f; uint32_t u; } v; v.f = f;
  return (unsigned short)((v.u + 0x7FFFu + ((v.u >> 16) & 1u)) >> 16);  // RNE
}

// ---------------- prep: W -> WtT tiled [24 it][192 r][40 shorts] (pad 8) ----
// element (it,r,c) = W_{r/64}[(it*32+c)*64 + (r&63)] ; Wq pre-scaled 1/8.
// R6: co-fastest lane mapping -> coalesced 256B reads; scattered 2B writes
// are L2-absorbed (WtT = 294KB, lines merged across c).
__global__ void wt_prep(const float* __restrict__ Wq, const float* __restrict__ Wk,
                        const float* __restrict__ Wv, unsigned short* __restrict__ WtT) {
  int idx = blockIdx.x * 256 + threadIdx.x;  // 24*3*32*64 = 147456
  if (idx >= 147456) return;
  int co = idx & 63;
  int c = (idx >> 6) & 31;
  int itm = idx >> 11;          // 0..71
  int it = itm / 3;
  int m = itm - it * 3;
  const float* W = (m == 0) ? Wq : (m == 1 ? Wk : Wv);
  float v = W[(it * 32 + c) * 64 + co];
  if (m == 0) v *= 0.125f;  // fold 1/sqrt(H) into Wq
  WtT[it * 7680 + (m * 64 + co) * 40 + c] = f2bf(v);
}

// LDS layout (bytes):
//  [0,20480)       xs buf0 [256 rows][40 shorts]
//  [20480,40960)   xs buf1
//  [40960,56320)   ws buf0 [192 rows][40 shorts]
//  [56320,71680)   ws buf1
//  [71680,104448)  K  [256 keys][64 h]  stride 128B, swz ^((key&7)<<4)
//  [104448,137216) Vt [64 h][256 t]     stride 512B, swz ^((h&7)<<4)
//  overlays (phase 2): Q [256 rows][256B] swz ^((row&15)<<4) at [0,65536)
//                      P: wave w uses [w*8192,+8192) = [16 rows][512B]
//                         swz ^((lrow&7)<<4)
#define XS0 0
#define XS1 20480
#define WS0 40960
#define WS1 56320
#define KOFF 71680
#define VOFF 104448

__global__ __launch_bounds__(512, 2) void fused_head(
    const float* __restrict__ x, const unsigned short* __restrict__ WtT,
    float* __restrict__ out) {
  __shared__ char smem[137216];
  const int tid = threadIdx.x;
  const int w = tid >> 6;
  const int lane = tid & 63;
  const int l15 = lane & 15, g = lane >> 4;
  const int b = blockIdx.x;
  const float* xB = x + (size_t)b * 256 * 768;

  char* xs0 = smem + XS0;
  char* xs1 = smem + XS1;
  char* ws0 = smem + WS0;
  char* ws1 = smem + WS1;

  // ---------------- phase 1: QKV projection ----------------
  f32x4 acc[2][12];
  #pragma unroll
  for (int rt = 0; rt < 2; ++rt)
    #pragma unroll
    for (int ct = 0; ct < 12; ++ct) acc[rt][ct] = f32x4{0.f, 0.f, 0.f, 0.f};

  const int sxr = tid >> 3;   // x staging: row within 64-row band
  const int sxc = tid & 7;    // 16B chunk
  const bool stv = (tid < 480);

  float4 xA[4], xPB[4];
  short8 wA[2], wPB[2];

  auto loadX = [&](float4* xr, int kk) {
    #pragma unroll
    for (int p = 0; p < 4; ++p)
      xr[p] = *reinterpret_cast<const float4*>(
          xB + (size_t)(p * 64 + sxr) * 768 + kk + sxc * 4);
  };
  auto loadW = [&](short8* wr, int it) {
    if (stv) {
      const short8* s = reinterpret_cast<const short8*>(WtT + (size_t)it * 7680 + tid * 16);
      wr[0] = s[0]; wr[1] = s[1];
    }
  };
  auto storeX = [&](char* xsb, const float4* xr) {
    #pragma unroll
    for (int p = 0; p < 4; ++p) {
      short4v v;
      v[0] = (short)f2bf(xr[p].x); v[1] = (short)f2bf(xr[p].y);
      v[2] = (short)f2bf(xr[p].z); v[3] = (short)f2bf(xr[p].w);
      *reinterpret_cast<short4v*>(xsb + (p * 64 + sxr) * 80 + sxc * 8) = v;
    }
  };
  auto storeW = [&](char* wsb, const short8* wr) {
    if (stv) {
      *reinterpret_cast<short8*>(wsb + tid * 32) = wr[0];
      *reinterpret_cast<short8*>(wsb + tid * 32 + 16) = wr[1];
    }
  };
  auto compute = [&](const char* xsb, const char* wsb) {
    short8 a0 = *reinterpret_cast<const short8*>(xsb + (w * 32 + l15) * 80 + g * 16);
    short8 a1 = *reinterpret_cast<const short8*>(xsb + (w * 32 + 16 + l15) * 80 + g * 16);
    #pragma unroll
    for (int ct = 0; ct < 12; ++ct) {
      short8 bb = *reinterpret_cast<const short8*>(wsb + (ct * 16 + l15) * 80 + g * 16);
      acc[0][ct] = MFMA16(a0, bb, acc[0][ct]);
      acc[1][ct] = MFMA16(a1, bb, acc[1][ct]);
    }
  };

  // prologue: tile0 -> LDS buf0 ; tile1 -> regs (B sets)
  loadX(xA, 0); loadW(wA, 0);
  storeX(xs0, xA); storeW(ws0, wA);
  loadX(xPB, 32); loadW(wPB, 1);
  BAR();

  for (int j = 0; j < 12; ++j) {
    // even iter: compute tile 2j from buf0; prefetch tile 2j+2 -> A
    if (2 * j + 2 < 24) { loadX(xA, (2 * j + 2) * 32); loadW(wA, 2 * j + 2); }
    compute(xs0, ws0);
    storeX(xs1, xPB); storeW(ws1, wPB);
    BAR();
    // odd iter: compute tile 2j+1 from buf1; prefetch tile 2j+3 -> B
    if (2 * j + 3 < 24) { loadX(xPB, (2 * j + 3) * 32); loadW(wPB, 2 * j + 3); }
    compute(xs1, ws1);
    if (2 * j + 2 < 24) { storeX(xs0, xA); storeW(ws0, wA); }
    BAR();
  }

  // ---------------- epilogue: accs -> LDS (K, Vt, Q) ----------------
  char* Kl = smem + KOFF;
  char* Vl = smem + VOFF;
  char* Ql = smem;
  #pragma unroll
  for (int rt = 0; rt < 2; ++rt) {
    #pragma unroll
    for (int ct = 0; ct < 4; ++ct) {
      #pragma unroll
      for (int r = 0; r < 4; ++r) {
        int key = w * 32 + rt * 16 + g * 4 + r;
        int h = ct * 16 + l15;
        *reinterpret_cast<unsigned short*>(
            Kl + key * 128 + ((h * 2) ^ ((key & 7) << 4))) = f2bf(acc[rt][4 + ct][r]);
        *reinterpret_cast<unsigned short*>(
            Ql + key * 256 + ((h * 2) ^ ((key & 15) << 4))) = f2bf(acc[rt][ct][r]);
      }
      int h = ct * 16 + l15;
      int t0 = w * 32 + rt * 16 + g * 4;
      short4v pv;
      pv[0] = (short)f2bf(acc[rt][8 + ct][0]); pv[1] = (short)f2bf(acc[rt][8 + ct][1]);
      pv[2] = (short)f2bf(acc[rt][8 + ct][2]); pv[3] = (short)f2bf(acc[rt][8 + ct][3]);
      *reinterpret_cast<short4v*>(Vl + h * 512 + ((t0 * 2) ^ ((h & 7) << 4))) = pv;
    }
  }
  BAR();  // K/V/Q visible to all waves

  // read Q fragments for this wave's two (balanced) q-tiles: w and 15-w
  short8 qf[2][2];
  #pragma unroll
  for (int rt = 0; rt < 2; ++rt) {
    const int qrow0 = (rt == 0) ? w * 16 : (15 - w) * 16;
    #pragma unroll
    for (int c = 0; c < 2; ++c) {
      int row = qrow0 + l15;
      qf[rt][c] = *reinterpret_cast<const short8*>(
          Ql + row * 256 + ((c * 64 + g * 16) ^ ((row & 15) << 4)));
    }
  }
  BAR();  // ALL qf reads done before ANY P write (P overlays the Q region)

  // ---------------- phase 2: causal attention ----------------
  char* Pw = smem + w * 8192;  // [16 rows][512B], swz ^((lrow&7)<<4)

  #pragma unroll
  for (int rt = 0; rt < 2; ++rt) {
    const int tile_idx = (rt == 0) ? w : 15 - w;
    const int trow0 = tile_idx * 16;
    const int ntile = tile_idx + 1;  // causal: key tiles 0..ntile-1
    const int pswz = (l15 & 7) << 4;

    // S^T = K Q^T : D row = key-local (g*4+r), col = q-local (l15)
    f32x4 s[16];
    #pragma unroll
    for (int t = 0; t < 16; ++t) {
      if (t < ntile) {
        int key = t * 16 + l15;
        int kswz = (key & 7) << 4;
        short8 k0 = *reinterpret_cast<const short8*>(Kl + key * 128 + ((g * 16) ^ kswz));
        short8 k1 = *reinterpret_cast<const short8*>(Kl + key * 128 + ((64 + g * 16) ^ kswz));
        f32x4 a = f32x4{0.f, 0.f, 0.f, 0.f};
        a = MFMA16(k0, qf[rt][0], a);
        a = MFMA16(k1, qf[rt][1], a);
        s[t] = a;
      }
    }

    // exp (no max-sub: scores bounded), mask diagonal, write P unnormalized
    // (4 consecutive keys/lane -> b64), accumulate sum.
    float sum = 0.f;
    #pragma unroll
    for (int t = 0; t < 16; ++t) {
      if (t < ntile) {
        const bool diag = (t == ntile - 1);
        short4v pk;
        #pragma unroll
        for (int r = 0; r < 4; ++r) {
          float p = __expf(s[t][r]);
          if (diag && (g * 4 + r > l15)) p = 0.f;  // causal mask
          sum += p;
          pk[r] = (short)f2bf(p);
        }
        *reinterpret_cast<short4v*>(Pw + l15 * 512 + ((t * 32 + g * 8) ^ pswz)) = pk;
      }
    }
    if (ntile & 1) {  // zero-pad tile ntile so the last 32-key PV chunk is clean
      *reinterpret_cast<short4v*>(Pw + l15 * 512 + ((ntile * 32 + g * 8) ^ pswz)) =
          short4v{0, 0, 0, 0};
    }
    sum += __shfl_xor(sum, 16);
    sum += __shfl_xor(sum, 32);
    const float inv = 1.0f / sum;  // denominator for q-row (trow0 + l15)

    // O^T = (P V)^T via operand swap: D row = h-local (g*4+r), col = q (l15)
    const int nkc = (ntile + 1) >> 1;
    f32x4 o[4];
    #pragma unroll
    for (int i = 0; i < 4; ++i) o[i] = f32x4{0.f, 0.f, 0.f, 0.f};
    #pragma unroll
    for (int kc = 0; kc < 8; ++kc) {
      if (kc < nkc) {
        short8 pa = *reinterpret_cast<const short8*>(
            Pw + l15 * 512 + ((kc * 64 + g * 16) ^ pswz));
        #pragma unroll
        for (int ht = 0; ht < 4; ++ht) {
          int h = ht * 16 + l15;
          short8 bv = *reinterpret_cast<const short8*>(
              Vl + h * 512 + ((kc * 64 + g * 16) ^ ((h & 7) << 4)));
          o[ht] = MFMA16(bv, pa, o[ht]);  // swapped: A=V^T rows, B=P rows
        }
      }
    }

    // store out fp32: lane holds O[q=trow0+l15][h = ht*16 + g*4 .. +4]
    {
      float* dst = out + ((size_t)b * 256 + trow0 + l15) * 64 + g * 4;
      #pragma unroll
      for (int ht = 0; ht < 4; ++ht) {
        float4 ov;
        ov.x = o[ht][0] * inv; ov.y = o[ht][1] * inv;
        ov.z = o[ht][2] * inv; ov.w = o[ht][3] * inv;
        *reinterpret_cast<float4*>(dst + ht * 16) = ov;
      }
    }
  }
}

// ---------------------------------------------------------------- launch
extern "C" void kernel_launch(void* const* d_in, const int* in_sizes, int n_in,
                              void* d_out, int out_size, void* d_ws, size_t ws_size,
                              hipStream_t stream) {
  const float* x  = (const float*)d_in[0];
  const float* Wq = (const float*)d_in[1];
  const float* Wk = (const float*)d_in[2];
  const float* Wv = (const float*)d_in[3];
  unsigned short* WtT = (unsigned short*)d_ws;  // 24*7680*2 = 368640 B
  float* out = (float*)d_out;

  hipLaunchKernelGGL(wt_prep, dim3(576), dim3(256), 0, stream, Wq, Wk, Wv, WtT);
  hipLaunchKernelGGL(fused_head, dim3(256), dim3(512), 0, stream, x, WtT, out);
}